// Round 4
// baseline (209.111 us; speedup 1.0000x reference)
//
#include <hip/hip_runtime.h>
#include <hip/hip_bf16.h>

// Head attention: B=16, T=2048, C=512(n_embd), H=64(head)
// out[b,t,h] = softmax_causal( (x@Wq)(x@Wk)^T * C^-0.5 ) @ (x@Wv)

#define B_ 16
#define T_ 2048
#define C_ 512
#define PSTR 80   // P LDS row stride (elems): 16B-aligned reads, bank-balanced

typedef __attribute__((ext_vector_type(4))) float f32x4;
typedef __attribute__((ext_vector_type(8))) short bf16x8;
typedef __attribute__((ext_vector_type(4))) short bf16x4;

__device__ inline unsigned short f2bf(float f) {
    unsigned int u = __builtin_bit_cast(unsigned int, f);
    u += 0x7fff + ((u >> 16) & 1);   // RNE
    return (unsigned short)(u >> 16);
}

__device__ inline f32x4 mfma16(bf16x8 a, bf16x8 b, f32x4 c) {
    return __builtin_amdgcn_mfma_f32_16x16x32_bf16(a, b, c, 0, 0, 0);
}

// ---------------------------------------------------------------------------
// prep: Wt[n][k] = W[k][n] bf16 (n: 0-63 K, 64-127 Q scaled, 128-191 V).
// Q scale folds 1/sqrt(512) AND log2(e): scores come out in log2 domain.
// Block 384: end-token scan (fe pre-initialized to big via memset).
// ---------------------------------------------------------------------------
__global__ void prep_kernel(const float* __restrict__ Wk, const float* __restrict__ Wq,
                            const float* __restrict__ Wv, const int* __restrict__ idx,
                            unsigned short* __restrict__ Wt, int* __restrict__ fe) {
    if (blockIdx.x == 384) {
#pragma unroll 4
        for (int i = threadIdx.x; i < B_ * T_; i += 256)
            if (idx[i] == 32000) atomicMin(&fe[i >> 11], i & 2047);
        return;
    }
    int id = blockIdx.x * 256 + threadIdx.x;     // [0, 3*32768)
    int mtx = id >> 15, rem = id & 32767;
    int k = rem >> 6, nl = rem & 63;
    const float* W = (mtx == 0) ? Wk : ((mtx == 1) ? Wq : Wv);
    float v = W[rem];                            // coalesced read
    if (mtx == 1) v *= 0.04419417382415922f * 1.4426950408889634f;  // /sqrt(512)*log2e
    Wt[(mtx * 64 + nl) * 512 + k] = f2bf(v);
}

// ---------------------------------------------------------------------------
// qkv: 64 tokens/block (unchanged from R3 — awaiting counters).
// ---------------------------------------------------------------------------
__global__ __launch_bounds__(256) void qkv_kernel(
        const float* __restrict__ x, const unsigned short* __restrict__ Wt,
        unsigned short* __restrict__ Qm, unsigned short* __restrict__ Km,
        unsigned short* __restrict__ Vt) {
    __shared__ __align__(16) unsigned short xs[64 * 512];   // 64 KB
    int tid = threadIdx.x, wave = tid >> 6, lane = tid & 63;
    int m16 = lane & 15, quad = lane >> 4;
    int row0 = blockIdx.x * 64;

#pragma unroll
    for (int i = 0; i < 16; i++) {
        int u = tid + i * 256;
        int row = u >> 6, cu = u & 63;
        const f32x4* p = (const f32x4*)(x + (long)(row0 + row) * C_ + cu * 8);
        f32x4 a = p[0], bq = p[1];
        bf16x8 t;
#pragma unroll
        for (int j = 0; j < 4; j++) { t[j] = (short)f2bf(a[j]); t[4 + j] = (short)f2bf(bq[j]); }
        *(bf16x8*)&xs[row * 512 + ((cu ^ (row & 7)) * 8)] = t;
    }
    __syncthreads();

    f32x4 ka[4], qa[4], va[4];
#pragma unroll
    for (int i = 0; i < 4; i++) {
        ka[i] = (f32x4){0.f, 0.f, 0.f, 0.f};
        qa[i] = (f32x4){0.f, 0.f, 0.f, 0.f};
        va[i] = (f32x4){0.f, 0.f, 0.f, 0.f};
    }
    int krw = (wave * 16 + m16) * 512;
    int qrw = (64 + wave * 16 + m16) * 512;
    int vrw = (128 + wave * 16 + m16) * 512;

#pragma unroll 2
    for (int cb = 0; cb < 8; cb++) {
#pragma unroll
        for (int half = 0; half < 2; half++) {
            int kk = cb * 64 + half * 32 + quad * 8;
            bf16x8 wk = *(const bf16x8*)&Wt[krw + kk];
            bf16x8 wq = *(const bf16x8*)&Wt[qrw + kk];
            bf16x8 wv = *(const bf16x8*)&Wt[vrw + kk];
            int g = kk >> 3;
            bf16x8 xf[4];
#pragma unroll
            for (int mt = 0; mt < 4; mt++) {
                int row = mt * 16 + m16;
                xf[mt] = *(const bf16x8*)&xs[row * 512 + ((g ^ (row & 7)) * 8)];
            }
#pragma unroll
            for (int mt = 0; mt < 4; mt++) ka[mt] = mfma16(xf[mt], wk, ka[mt]);
#pragma unroll
            for (int mt = 0; mt < 4; mt++) qa[mt] = mfma16(xf[mt], wq, qa[mt]);
#pragma unroll
            for (int mt = 0; mt < 4; mt++) va[mt] = mfma16(wv, xf[mt], va[mt]);  // V^T
        }
    }
    __syncthreads();

    unsigned short* co  = xs;                    // [64][136] K|Q
    unsigned short* vco = xs + 64 * 136;         // [4][16][72] V^T
#pragma unroll
    for (int mt = 0; mt < 4; mt++) {
#pragma unroll
        for (int r = 0; r < 4; r++) {
            int trow = mt * 16 + quad * 4 + r;
            co[trow * 136 + wave * 16 + m16]      = f2bf(ka[mt][r]);
            co[trow * 136 + 64 + wave * 16 + m16] = f2bf(qa[mt][r]);
            vco[wave * 1152 + (quad * 4 + r) * 72 + mt * 16 + m16] = f2bf(va[mt][r]);
        }
    }
    __syncthreads();
#pragma unroll
    for (int i = 0; i < 4; i++) {
        int u = tid + i * 256; int tok = u >> 4; int fg = u & 15;
        bf16x8 vv = *(const bf16x8*)&co[tok * 136 + fg * 8];
        unsigned short* dst = (fg < 8) ? Km : Qm;
        *(bf16x8*)&dst[(long)(row0 + tok) * 64 + (fg & 7) * 8] = vv;
    }
    int bb = row0 >> 11, tl = row0 & 2047;
#pragma unroll
    for (int i = 0; i < 2; i++) {
        int u = lane + i * 64; int hl = u >> 3; int tg = u & 7;
        bf16x8 vv = *(const bf16x8*)&vco[wave * 1152 + hl * 72 + tg * 8];
        *(bf16x8*)&Vt[((long)bb * 64 + wave * 16 + hl) * T_ + tl + tg * 8] = vv;
    }
}

// ---------------------------------------------------------------------------
// attn v4: S^T formulation + split-K wave pairs.
//   Wave pair (2 waves) owns one 16-row q-tile; waveH=0 takes key tiles
//   [0,half), waveH=1 takes [half,ntiles) incl. diagonal; merged via LDS.
//   S^T = K·Q^T: C-layout col=q=m16 -> per-lane softmax state, 2-shfl max,
//   P packed as 4 ds_write_b64; O^T = V^T·P^T; denominator via all-ones
//   A-frag (every lane holds l, no broadcast). Grid (16,64): q-tiles paired
//   {y,127-y} for equal block work; 4 blocks/CU = 16 waves/CU.
// ---------------------------------------------------------------------------
__global__ __launch_bounds__(256, 4) void attn_kernel(
        const unsigned short* __restrict__ Qm, const unsigned short* __restrict__ Km,
        const unsigned short* __restrict__ Vt, const int* __restrict__ fe,
        float* __restrict__ out) {
    __shared__ __align__(16) unsigned short Plds[4][16 * PSTR];
    __shared__ float MO[2][64 * 16];             // waveH=0 partial O^T [h][q]
    __shared__ float ML[2][2][16];               // waveH=0 partial m, l

    int b = blockIdx.x;                          // XCD = b%8 -> K/V L2-local
    int y = blockIdx.y;
    int tid = threadIdx.x, wave = tid >> 6, lane = tid & 63;
    int m16 = lane & 15, quad = lane >> 4;
    int pair = wave >> 1, waveH = wave & 1;
    int qt16 = pair ? y : (127 - y);             // paired big+small tiles
    int qrow0 = qt16 << 4;
    long bT = (long)b * T_;

    int nfull = qt16 >> 2;                       // diagonal tile index
    int ntiles = nfull + 1;
    int half = ntiles >> 1;
    int lo = waveH ? half : 0;
    int hi = waveH ? ntiles : half;

    const unsigned short* qp = Qm + (bT + qrow0 + m16) * 64;
    bf16x8 qf0 = *(const bf16x8*)(qp + quad * 8);        // B-frag of Q^T
    bf16x8 qf1 = *(const bf16x8*)(qp + 32 + quad * 8);

    const unsigned short* Kbase = Km + bT * 64;
    const unsigned short* Vbase = Vt + (long)b * 64 * T_;

    f32x4 o[5];
#pragma unroll
    for (int h = 0; h < 5; h++) o[h] = (f32x4){0.f, 0.f, 0.f, 0.f};
    float mi = -INFINITY;                        // per-lane: q = m16
    int q_abs = qrow0 + m16;

    bf16x8 onesa;                                // all-ones A-frag (denominator)
#pragma unroll
    for (int j = 0; j < 8; j++) onesa[j] = (short)0x3F80;

    unsigned short* pw = Plds[wave];

    for (int kt = lo; kt < hi; kt++) {
        bf16x8 kf[8];                            // K A-frags
#pragma unroll
        for (int ns = 0; ns < 4; ns++)
#pragma unroll
            for (int h = 0; h < 2; h++)
                kf[ns * 2 + h] = *(const bf16x8*)
                    &Kbase[(kt * 64 + ns * 16 + m16) * 64 + h * 32 + quad * 8];

        f32x4 s[4];                              // S^T: row=key, col=q=m16
#pragma unroll
        for (int ns = 0; ns < 4; ns++) {
            f32x4 z = (f32x4){0.f, 0.f, 0.f, 0.f};
            z = mfma16(kf[ns * 2], qf0, z);
            z = mfma16(kf[ns * 2 + 1], qf1, z);
            s[ns] = z;
        }

        bf16x8 vf[8];                            // V^T A-frags (used after softmax)
#pragma unroll
        for (int hs = 0; hs < 4; hs++)
#pragma unroll
            for (int h = 0; h < 2; h++)
                vf[hs * 2 + h] = *(const bf16x8*)
                    &Vbase[(hs * 16 + m16) * T_ + kt * 64 + h * 32 + quad * 8];

        if (kt == nfull) {                       // causal mask on diagonal tile
#pragma unroll
            for (int ns = 0; ns < 4; ns++) {
                int kb = kt * 64 + ns * 16 + quad * 4;
#pragma unroll
                for (int r = 0; r < 4; r++)
                    if (kb + r > q_abs) s[ns][r] = -INFINITY;
            }
        }

        // per-lane softmax over 16 keys (scores already in log2 domain)
        f32x4 t01, t;
#pragma unroll
        for (int r = 0; r < 4; r++) t01[r] = fmaxf(s[0][r], s[1][r]);
#pragma unroll
        for (int r = 0; r < 4; r++) t[r] = fmaxf(t01[r], fmaxf(s[2][r], s[3][r]));
        float mx = fmaxf(fmaxf(t[0], t[1]), fmaxf(t[2], t[3]));
        mx = fmaxf(mx, __shfl_xor(mx, 16));
        mx = fmaxf(mx, __shfl_xor(mx, 32));
        mx = fmaxf(mx, mi);
        float alpha = exp2f(mi - mx);
        mi = mx;
#pragma unroll
        for (int ns = 0; ns < 4; ns++)
#pragma unroll
            for (int r = 0; r < 4; r++) s[ns][r] = exp2f(s[ns][r] - mx);
#pragma unroll
        for (int h = 0; h < 5; h++) o[h] *= alpha;

        // P^T -> LDS [q=m16][key], 4x ds_write_b64 (consecutive keys)
#pragma unroll
        for (int ns = 0; ns < 4; ns++) {
            bf16x4 pk;
#pragma unroll
            for (int r = 0; r < 4; r++) pk[r] = (short)f2bf(s[ns][r]);
            *(bf16x4*)&pw[m16 * PSTR + ns * 16 + quad * 4] = pk;
        }
        bf16x8 pb0 = *(const bf16x8*)&pw[m16 * PSTR + quad * 8];        // B-frags
        bf16x8 pb1 = *(const bf16x8*)&pw[m16 * PSTR + 32 + quad * 8];

#pragma unroll
        for (int hs = 0; hs < 4; hs++) {         // O^T += V^T P^T
            o[hs] = mfma16(vf[hs * 2], pb0, o[hs]);
            o[hs] = mfma16(vf[hs * 2 + 1], pb1, o[hs]);
        }
        o[4] = mfma16(onesa, pb0, o[4]);         // l (all lanes, all regs)
        o[4] = mfma16(onesa, pb1, o[4]);
    }

    if (!waveH) {                                // publish partial
#pragma unroll
        for (int hs = 0; hs < 4; hs++)
#pragma unroll
            for (int r = 0; r < 4; r++)
                MO[pair][(hs * 16 + quad * 4 + r) * 16 + m16] = o[hs][r];
        if (quad == 0) { ML[pair][0][m16] = mi; ML[pair][1][m16] = o[4][0]; }
    }
    __syncthreads();
    if (waveH) {                                 // merge + store
        float m0 = ML[pair][0][m16], l0 = ML[pair][1][m16];
        float M = fmaxf(m0, mi);
        float a0 = exp2f(m0 - M);
        float a1 = exp2f(mi - M);
        float l = a0 * l0 + a1 * o[4][0];
        float inv = 1.0f / l;
        int t = qrow0 + m16;
        bool dead = (t >= fe[b]);
#pragma unroll
        for (int hs = 0; hs < 4; hs++) {
            f32x4 res;
#pragma unroll
            for (int r = 0; r < 4; r++) {
                float v = (a1 * o[hs][r] + a0 * MO[pair][(hs * 16 + quad * 4 + r) * 16 + m16]) * inv;
                res[r] = dead ? __builtin_nanf("") : v;
            }
            *(f32x4*)&out[(bT + t) * 64 + hs * 16 + quad * 4] = res;
        }
    }
}

// ---------------------------------------------------------------------------
extern "C" void kernel_launch(void* const* d_in, const int* in_sizes, int n_in,
                              void* d_out, int out_size, void* d_ws, size_t ws_size,
                              hipStream_t stream) {
    const float* x  = (const float*)d_in[0];
    const float* Wk = (const float*)d_in[1];
    const float* Wq = (const float*)d_in[2];
    const float* Wv = (const float*)d_in[3];
    const int* idx  = (const int*)d_in[4];
    float* out = (float*)d_out;

    char* ws = (char*)d_ws;
    int* fe            = (int*)ws;                                 //    64 B
    unsigned short* Wt = (unsigned short*)(ws + 1024);             //  192 KiB
    unsigned short* Qm = (unsigned short*)(ws + 262144);           //    4 MiB
    unsigned short* Km = (unsigned short*)(ws + 262144 + 4194304); //    4 MiB
    unsigned short* Vt = (unsigned short*)(ws + 262144 + 8388608); //    4 MiB

    hipMemsetAsync(fe, 0x7F, 64, stream);        // fe init > 2047
    prep_kernel<<<385, 256, 0, stream>>>(Wk, Wq, Wv, idx, Wt, fe);
    qkv_kernel<<<512, 256, 0, stream>>>(x, Wt, Qm, Km, Vt);
    dim3 ga(16, 64);
    attn_kernel<<<ga, 256, 0, stream>>>(Qm, Km, Vt, fe, out);
}